// Round 9
// baseline (186.139 us; speedup 1.0000x reference)
//
#include <hip/hip_runtime.h>
#include <hip/hip_bf16.h>
#include <math.h>

#define NTOK 1600
#define CDIM 256
#define DK   64

typedef __attribute__((ext_vector_type(8))) short bf16x8;
typedef __attribute__((ext_vector_type(4))) float f32x4;

__device__ inline unsigned short f2bf(float v) {
    unsigned int u = __float_as_uint(v);
    unsigned int r = (u + 0x7fffu + ((u >> 16) & 1u)) >> 16;
    return (unsigned short)r;
}

// LDS-only barrier: drains LDS ops but leaves global loads in flight
// (cross-wave deps in our loops are only through LDS).
__device__ inline void lgkm_barrier() {
    asm volatile("s_waitcnt lgkmcnt(0)" ::: "memory");
    __builtin_amdgcn_s_barrier();
    asm volatile("" ::: "memory");
}

// ---------------------------------------------------------------------------
// Kernel A: geometric relation table, wave-per-idx (1600 waves, 400 blocks).
// ---------------------------------------------------------------------------
__global__ __launch_bounds__(256) void geo_table_kernel(
    const float* __restrict__ W1, const float* __restrict__ b1,
    const float* __restrict__ W2, const float* __restrict__ b2,
    const float* __restrict__ Wgr, const float* __restrict__ bgr,
    float* __restrict__ table)
{
    __shared__ float e1s[4][64];
    __shared__ float e2s[4][64];
    int t = threadIdx.x;
    int w = t >> 6, j = t & 63;
    int idx = blockIdx.x * 4 + w;
    int ady = idx / 40, adx = idx % 40;
    float g0 = logf((float)adx + 1e-8f);
    float g1 = logf((float)ady + 1e-8f);
    float gc = logf(1e-8f);

    float e1 = fmaxf(g0*W1[j] + g1*W1[64+j] + gc*(W1[128+j]+W1[192+j]) + b1[j], 0.f);
    e1s[w][j] = e1;
    __syncthreads();

    float e2 = b2[j];
    #pragma unroll 8
    for (int i = 0; i < 64; ++i) e2 += e1s[w][i] * W2[i*64 + j];
    e2 = fmaxf(e2, 0.f);
    e2s[w][j] = e2;
    __syncthreads();

    int r = j & 15, q = j >> 4;
    float v = (q == 0) ? bgr[r] : 0.f;
    #pragma unroll
    for (int i = 0; i < 16; ++i) v += e2s[w][q*16 + i] * Wgr[(q*16 + i)*16 + r];
    v += __shfl_xor(v, 16); v += __shfl_xor(v, 32);
    v = fmaxf(v, 0.f);
    v += __shfl_xor(v, 1); v += __shfl_xor(v, 2);
    v += __shfl_xor(v, 4); v += __shfl_xor(v, 8);
    if (j == 0) table[idx] = v * (1.f / 16.f);
}

// ---------------------------------------------------------------------------
// Kernel B: QKV projection via bf16 MFMA. 512 thr = 8 waves.
// Staging: threads 0-255 stage As (from x), 256-511 stage Bs (from Wm);
// each thread owns one row g and a 16-k block: 16 scalar f32 coalesced loads,
// 4 packed uint2 bf16 LDS writes. Register double-buffer across k-tiles;
// lgkm-only barriers keep prefetch loads in flight.
// MFMA: wave w -> n-panel (w>>1) x j-half (w&1), acc[2].
// grid (25 ntiles, 6 jt, 4 b).
// ---------------------------------------------------------------------------
__global__ __launch_bounds__(512) void qkv_kernel(
    const float* __restrict__ x,
    const float* __restrict__ Wq, const float* __restrict__ bq,
    const float* __restrict__ Wk, const float* __restrict__ bk,
    const float* __restrict__ Wv, const float* __restrict__ bv,
    unsigned short* __restrict__ Qb, unsigned short* __restrict__ Kb,
    unsigned short* __restrict__ Vt)
{
    const int N = NTOK;
    int bx = blockIdx.x, jt = blockIdx.y, b = blockIdx.z;
    const float* Wm; const float* bias; int jb, stride;
    if (jt == 0)      { Wm = Wq; bias = bq; jb = 0;         stride = 64;  }
    else if (jt == 1) { Wm = Wk; bias = bk; jb = 0;         stride = 64;  }
    else              { Wm = Wv; bias = bv; jb = (jt-2)*64; stride = 256; }

    __shared__ __align__(16) unsigned short As[64*72];   // [n][k] pad 72
    __shared__ __align__(16) unsigned short Bs[64*72];   // [j][k] pad 72

    int t = threadIdx.x;
    int w = t >> 6, l = t & 63;
    int l15 = l & 15, l4 = l >> 4;
    int panel = w >> 1;          // n-panel 0..3 (MFMA phase)
    int jhalf = w & 1;           // j-half 0..1
    int n0 = bx * 64;

    // staging role
    int g  = t & 63;             // row within tile (n for As, j for Bs)
    int kq = (t & 255) >> 6;     // k-block of 16
    bool isA = (t < 256);

    float rcur[16], rnxt[16];

    #define QKV_LOAD(k0g, dst)                                                   \
        if (isA) {                                                               \
            const float* base_ = &x[((size_t)(b*CDIM) + (k0g) + kq*16)*N + n0 + g]; \
            _Pragma("unroll")                                                    \
            for (int kk = 0; kk < 16; ++kk) (dst)[kk] = base_[(size_t)kk*N];     \
        } else {                                                                 \
            const float* base_ = &Wm[(size_t)((k0g) + kq*16)*stride + jb + g];   \
            _Pragma("unroll")                                                    \
            for (int kk = 0; kk < 16; ++kk) (dst)[kk] = base_[(size_t)kk*stride];\
        }

    QKV_LOAD(0, rcur);

    f32x4 acc[2];
    acc[0] = (f32x4){0.f,0.f,0.f,0.f};
    acc[1] = (f32x4){0.f,0.f,0.f,0.f};

    unsigned short* dstT = isA ? As : Bs;

    #pragma unroll
    for (int kc = 0; kc < 4; ++kc) {
        lgkm_barrier();                       // prior tile's MFMA LDS reads done
        // packed bf16 writes: 4 x uint2 per thread
        #pragma unroll
        for (int jq = 0; jq < 4; ++jq) {
            __align__(8) unsigned short u[4];
            #pragma unroll
            for (int i2 = 0; i2 < 4; ++i2) u[i2] = f2bf(rcur[jq*4 + i2]);
            *(uint2*)&dstT[g*72 + kq*16 + jq*4] = *(const uint2*)u;
        }
        // prefetch next tile (wraps to 0 on last iter; dead but harmless)
        QKV_LOAD(kc < 3 ? (kc+1)*64 : 0, rnxt);
        lgkm_barrier();                       // staged tile visible

        #pragma unroll
        for (int ks = 0; ks < 2; ++ks) {
            bf16x8 a = *(const bf16x8*)&As[(panel*16 + l15)*72 + ks*32 + l4*8];
            #pragma unroll
            for (int jj = 0; jj < 2; ++jj) {
                bf16x8 bf = *(const bf16x8*)&Bs[(jhalf*32 + jj*16 + l15)*72 + ks*32 + l4*8];
                acc[jj] = __builtin_amdgcn_mfma_f32_16x16x32_bf16(a, bf, acc[jj], 0, 0, 0);
            }
        }
        #pragma unroll
        for (int i = 0; i < 16; ++i) rcur[i] = rnxt[i];
    }

    if (jt <= 1) {
        unsigned short* outb = (jt == 0 ? Qb : Kb) + (size_t)b*N*DK;
        float scale = (jt == 0) ? 0.125f : 1.0f;
        #pragma unroll
        for (int jj = 0; jj < 2; ++jj) {
            int j = jhalf*32 + jj*16 + l15;
            float bb = bias[j];
            #pragma unroll
            for (int r = 0; r < 4; ++r) {
                int n = n0 + panel*16 + l4*4 + r;
                outb[(size_t)n*DK + j] = f2bf((acc[jj][r] + bb) * scale);
            }
        }
    } else {
        __syncthreads();
        // stage full 64c x 64n bf16 tile in As (stride 72)
        unsigned short* sv = As;
        #pragma unroll
        for (int jj = 0; jj < 2; ++jj) {
            int j = jhalf*32 + jj*16 + l15;
            float bb = bias[jb + j];
            #pragma unroll
            for (int r = 0; r < 4; ++r)
                sv[j*72 + panel*16 + l4*4 + r] = f2bf(acc[jj][r] + bb);
        }
        __syncthreads();
        // coalesced store: 8 lanes x 16B = one 128B row per c
        int c   = t >> 3;
        int off = (t & 7) * 8;
        uint4 v = *(const uint4*)&sv[c*72 + off];
        *(uint4*)&Vt[((size_t)b*CDIM + jb + c)*N + n0 + off] = v;
    }
}

// ---------------------------------------------------------------------------
// Kernel C: MFMA attention, c-split, register-prefetched K/V, lgkm-only
// barriers (global loads stay in flight across the per-chunk barrier).
// Block = (16 q-rows, 64-c slice, b); wave w: S sub-tile w + 16-c PV sub-tile.
// grid (100 ntiles, 4 c-slices, 4 b) = 1600 blocks, 256 thr.
// ---------------------------------------------------------------------------
__global__ __launch_bounds__(256) void attn_kernel(
    const float* __restrict__ x, const float* __restrict__ gtab,
    const unsigned short* __restrict__ Qb, const unsigned short* __restrict__ Kb,
    const unsigned short* __restrict__ Vt, float* __restrict__ out)
{
    const int N = NTOK, C = CDIM;
    int b = blockIdx.z, c0 = blockIdx.y * 64, n0 = blockIdx.x * 16;
    int t = threadIdx.x;
    int w = t >> 6, l = t & 63;
    int l15 = l & 15, l4 = l >> 4;

    __shared__ __align__(16) unsigned short Pl[2][16*72];  // shared P, dbuf
    __shared__ float sh_g[NTOK];
    __shared__ float shZ[4][16];
    __shared__ float zsum[16];
    __shared__ __align__(16) float outs[64*17];            // [c-local][n-local]

    for (int p = t; p < NTOK; p += 256) sh_g[p] = gtab[p];

    const unsigned short* qrow = &Qb[((size_t)b*N + n0 + l15)*DK + l4*8];
    bf16x8 qa0 = *(const bf16x8*)qrow;
    bf16x8 qa1 = *(const bf16x8*)(qrow + 32);

    f32x4 acc = (f32x4){0.f,0.f,0.f,0.f};
    float z[4] = {0.f, 0.f, 0.f, 0.f};

    int yn[4], xn[4];
    #pragma unroll
    for (int r = 0; r < 4; ++r) {
        int n = n0 + l4*4 + r;
        yn[r] = n / 40; xn[r] = n - 40*yn[r];
    }
    int mcol = w*16 + l15;   // this wave's key column within each 64-chunk

    // fragment base pointers (linear in m0)
    const unsigned short* kb_base = &Kb[((size_t)b*N + mcol)*DK + l4*8];       // + m0*64
    const unsigned short* vb_base = &Vt[((size_t)b*C + c0 + w*16 + l15)*N + l4*8]; // + m0

    // preload chunk 0
    bf16x8 kb0 = *(const bf16x8*)(kb_base);
    bf16x8 kb1 = *(const bf16x8*)(kb_base + 32);
    bf16x8 vb0 = *(const bf16x8*)(vb_base);
    bf16x8 vb1 = *(const bf16x8*)(vb_base + 32);

    __syncthreads();   // sh_g ready

    for (int cc = 0; cc < 25; ++cc) {
        int m0 = cc * 64;
        // ---- prefetch next chunk's K/V fragments (wrap on last iter) ----
        int mnext = (cc < 24) ? m0 + 64 : 0;
        const unsigned short* kp = kb_base + (size_t)mnext*64;
        const unsigned short* vp = vb_base + mnext;
        bf16x8 kn0 = *(const bf16x8*)(kp);
        bf16x8 kn1 = *(const bf16x8*)(kp + 32);
        bf16x8 vn0 = *(const bf16x8*)(vp);
        bf16x8 vn1 = *(const bf16x8*)(vp + 32);

        // ---- S phase: this wave's 16-key sub-tile ----
        f32x4 s4 = (f32x4){0.f,0.f,0.f,0.f};
        s4 = __builtin_amdgcn_mfma_f32_16x16x32_bf16(qa0, kb0, s4, 0, 0, 0);
        s4 = __builtin_amdgcn_mfma_f32_16x16x32_bf16(qa1, kb1, s4, 0, 0, 0);

        int mg = m0 + mcol;
        int ym = mg / 40, xm = mg - 40*ym;
        unsigned short* prow = &Pl[cc & 1][0];
        #pragma unroll
        for (int r = 0; r < 4; ++r) {
            float e = __expf(s4[r]);
            z[r] += e;
            int ady = ym - yn[r]; ady = ady < 0 ? -ady : ady;
            int adx = xm - xn[r]; adx = adx < 0 ? -adx : adx;
            prow[(l4*4 + r)*72 + mcol] = f2bf(e * sh_g[ady*40 + adx]);
        }
        lgkm_barrier();   // P visible; prefetch loads remain in flight

        // ---- PV phase: this wave's 16-c sub-tile ----
        const unsigned short* pb = &Pl[cc & 1][l15*72 + l4*8];
        bf16x8 pa0 = *(const bf16x8*)pb;
        bf16x8 pa1 = *(const bf16x8*)(pb + 32);
        acc = __builtin_amdgcn_mfma_f32_16x16x32_bf16(pa0, vb0, acc, 0, 0, 0);
        acc = __builtin_amdgcn_mfma_f32_16x16x32_bf16(pa1, vb1, acc, 0, 0, 0);

        kb0 = kn0; kb1 = kn1; vb0 = vn0; vb1 = vn1;
        // P double-buffered: no trailing barrier
    }

    // ---- z reduce: over 16 key-columns, then across waves ----
    #pragma unroll
    for (int r = 0; r < 4; ++r) {
        float v = z[r];
        v += __shfl_xor(v, 1); v += __shfl_xor(v, 2);
        v += __shfl_xor(v, 4); v += __shfl_xor(v, 8);
        if (l15 == 0) shZ[w][l4*4 + r] = v;
    }
    // ---- stash acc to LDS for the transpose ----
    #pragma unroll
    for (int r = 0; r < 4; ++r)
        outs[(w*16 + l15)*17 + l4*4 + r] = acc[r];
    __syncthreads();

    if (t < 16) zsum[t] = 1.f / (shZ[0][t] + shZ[1][t] + shZ[2][t] + shZ[3][t]);
    __syncthreads();

    // ---- epilogue: normalize + residual, 64B-per-c-row stores ----
    int c  = t >> 2;            // 0..63
    int nl = (t & 3) * 4;       // 0,4,8,12
    size_t gi = ((size_t)b*C + c0 + c)*N + n0 + nl;
    float4 xv = *(const float4*)&x[gi];
    float4 o;
    o.x = xv.x + outs[c*17 + nl + 0] * zsum[nl + 0];
    o.y = xv.y + outs[c*17 + nl + 1] * zsum[nl + 1];
    o.z = xv.z + outs[c*17 + nl + 2] * zsum[nl + 2];
    o.w = xv.w + outs[c*17 + nl + 3] * zsum[nl + 3];
    *(float4*)&out[gi] = o;
}

// ---------------------------------------------------------------------------
extern "C" void kernel_launch(void* const* d_in, const int* in_sizes, int n_in,
                              void* d_out, int out_size, void* d_ws, size_t ws_size,
                              hipStream_t stream)
{
    const float* x   = (const float*)d_in[0];
    const float* Wq  = (const float*)d_in[1];
    const float* bq  = (const float*)d_in[2];
    const float* Wk  = (const float*)d_in[3];
    const float* bk  = (const float*)d_in[4];
    const float* Wv  = (const float*)d_in[5];
    const float* bv  = (const float*)d_in[6];
    const float* Wg1 = (const float*)d_in[7];
    const float* bg1 = (const float*)d_in[8];
    const float* Wg2 = (const float*)d_in[9];
    const float* bg2 = (const float*)d_in[10];
    const float* Wgr = (const float*)d_in[11];
    const float* bgr = (const float*)d_in[12];

    char* ws = (char*)d_ws;
    float* table       = (float*)ws;                              // 6400 B
    unsigned short* Qb = (unsigned short*)(ws + 8192);            // 819200 B
    unsigned short* Kb = (unsigned short*)(ws + 8192 + 819200);
    unsigned short* Vt = (unsigned short*)(ws + 8192 + 2*819200); // 3276800 B

    geo_table_kernel<<<dim3(400), dim3(256), 0, stream>>>(Wg1, bg1, Wg2, bg2, Wgr, bgr, table);
    qkv_kernel<<<dim3(25, 6, 4), dim3(512), 0, stream>>>(x, Wq, bq, Wk, bk, Wv, bv, Qb, Kb, Vt);
    attn_kernel<<<dim3(100, 4, 4), dim3(256), 0, stream>>>(x, table, Qb, Kb, Vt, (float*)d_out);
}